// Round 1
// baseline (3983.241 us; speedup 1.0000x reference)
//
#include <hip/hip_runtime.h>

// Problem shape (fixed by setup_inputs): B=4, N=16384, NPOINT=1024, nsample=1,
// radius=0.5. xyz input layout is [B,3,N]. Output: int32 [B,NPOINT,1].
//
// FPS structure: one block per batch (cross-block sync per iteration would cost
// more than the whole iteration). 1024 threads (16 waves -> 4 waves/SIMD for
// latency hiding), 16 points/thread in registers as 8 packed f32x2 pairs.
// Per iteration:
//   value-only block max (pk math -> per-thread max tree -> f32 butterfly ->
//   LDS -> barrier -> 16-entry max) then index recovery: only waves whose max
//   equals the block max rescan registers for bit-equality and atomicMin the
//   global index into LDS (exact numpy argmax first-occurrence semantics),
//   barrier, readfirstlane.
// Distance math replicates numpy exactly: ((dx*dx+dy*dy)+dz*dz), each op RN,
// no FMA contraction (v_pk_add/v_pk_mul are per-half RN; subtraction done as
// add of exactly-negated centroid).

constexpr int N_PTS  = 16384;
constexpr int NPOINT = 1024;
constexpr int BLOCK  = 1024;           // 16 waves -> 4 waves/SIMD
constexpr int KPT    = N_PTS / BLOCK;  // 16 points/thread
constexpr int KP2    = KPT / 2;        // 8 register pairs
constexpr int NWAVE  = BLOCK / 64;     // 16

typedef float f32x2 __attribute__((ext_vector_type(2)));
typedef float f32x4 __attribute__((ext_vector_type(4)));

__device__ inline f32x2 pk_add(f32x2 a, f32x2 b) {
    f32x2 d;
    asm("v_pk_add_f32 %0, %1, %2" : "=v"(d) : "v"(a), "v"(b));
    return d;
}
__device__ inline f32x2 pk_mul(f32x2 a, f32x2 b) {
    f32x2 d;
    asm("v_pk_mul_f32 %0, %1, %2" : "=v"(d) : "v"(a), "v"(b));
    return d;
}

// max of the 16 per-wave maxima sitting in LDS (all-lane broadcast reads)
__device__ inline float lds_max16(const float* sm) {
    const f32x4* v4 = (const f32x4*)sm;
    const f32x4 a = v4[0], b = v4[1], c = v4[2], d = v4[3];
    const float m = fmaxf(fmaxf(fmaxf(a.x, a.y), fmaxf(a.z, a.w)),
                          fmaxf(fmaxf(b.x, b.y), fmaxf(b.z, b.w)));
    const float n = fmaxf(fmaxf(fmaxf(c.x, c.y), fmaxf(c.z, c.w)),
                          fmaxf(fmaxf(d.x, d.y), fmaxf(d.z, d.w)));
    return fmaxf(m, n);
}

__global__ __launch_bounds__(BLOCK, 4) void fps_kernel(
    const float* __restrict__ xyz,   // [B,3,N]
    int* __restrict__ cent)          // [B,NPOINT] workspace
{
    const int b   = blockIdx.x;
    const int tid = threadIdx.x;
    const float* X = xyz + (size_t)b * 3 * N_PTS;
    const float* Y = X + N_PTS;
    const float* Z = X + 2 * N_PTS;

    f32x2 px[KP2], py[KP2], pz[KP2], dd[KP2];
#pragma unroll
    for (int k = 0; k < KP2; ++k) {
        const int p0 = tid + (2 * k) * BLOCK;      // coalesced per component
        const int p1 = tid + (2 * k + 1) * BLOCK;
        px[k] = f32x2{X[p0], X[p1]};
        py[k] = f32x2{Y[p0], Y[p1]};
        pz[k] = f32x2{Z[p0], Z[p1]};
        dd[k] = f32x2{1e10f, 1e10f};               // BIG
    }

    __shared__ __align__(16) float s_max[2][NWAVE];
    __shared__ int s_win[2];

    const int wave = tid >> 6;
    const int lane = tid & 63;
    if (tid == 0) { s_win[0] = 0x7fffffff; s_win[1] = 0x7fffffff; }

    // ---- initial far: argmax over x (first occurrence) ----
    int far;
    {
        float bv = px[0].x;
#pragma unroll
        for (int k = 0; k < KP2; ++k) {
            bv = fmaxf(bv, px[k].x);
            bv = fmaxf(bv, px[k].y);
        }
#pragma unroll
        for (int off = 32; off > 0; off >>= 1)
            bv = fmaxf(bv, __shfl_xor(bv, off));
        if (lane == 0) s_max[1][wave] = bv;
        __syncthreads();                            // also publishes s_win init
        const float BV = lds_max16(s_max[1]);
        if (bv == BV) {                             // usually exactly one wave
            int cand = 0x7fffffff;
#pragma unroll
            for (int k = 0; k < KP2; ++k) {
                if (px[k].x == BV) cand = min(cand, tid + (2 * k) * BLOCK);
                if (px[k].y == BV) cand = min(cand, tid + (2 * k + 1) * BLOCK);
            }
            atomicMin(&s_win[1], cand);
        }
        __syncthreads();
        far = __builtin_amdgcn_readfirstlane(s_win[1]);
    }

    // ---- main FPS loop ----
    for (int it = 0; it < NPOINT; ++it) {
        if (tid == 0) cent[b * NPOINT + it] = far;  // record PRE-update far
        if (it == NPOINT - 1) break;                // last update unused
        const int buf = it & 1;

        // centroid coords: far is uniform (SGPR) -> scalar broadcast loads
        const float cx = X[far];
        const float cy = Y[far];
        const float cz = Z[far];
        const f32x2 ncx = {-cx, -cx};               // exact negation
        const f32x2 ncy = {-cy, -cy};
        const f32x2 ncz = {-cz, -cz};

#pragma unroll
        for (int k = 0; k < KP2; ++k) {
            const f32x2 dx = pk_add(px[k], ncx);    // == px - cx, RN
            const f32x2 dy = pk_add(py[k], ncy);
            const f32x2 dz = pk_add(pz[k], ncz);
            const f32x2 d  = pk_add(pk_add(pk_mul(dx, dx), pk_mul(dy, dy)),
                                    pk_mul(dz, dz));
            f32x2 nd;
            nd.x = fminf(dd[k].x, d.x);
            nd.y = fminf(dd[k].y, d.y);
            dd[k] = nd;
        }

        // per-thread max (two parallel chains), then wave butterfly on f32
        f32x2 m2 = dd[0];
#pragma unroll
        for (int k = 1; k < KP2; ++k) {
            m2.x = fmaxf(m2.x, dd[k].x);
            m2.y = fmaxf(m2.y, dd[k].y);
        }
        float bv = fmaxf(m2.x, m2.y);
#pragma unroll
        for (int off = 32; off > 0; off >>= 1)
            bv = fmaxf(bv, __shfl_xor(bv, off));
        if (lane == 0) s_max[buf][wave] = bv;
        __syncthreads();                            // barrier #1

        if (tid == 0) s_win[buf ^ 1] = 0x7fffffff;  // reset slot for NEXT iter
        const float BV = lds_max16(s_max[buf]);

        // index recovery: only waves holding the max rescan (bit-equality);
        // atomicMin gives global min index among ties == numpy argmax.
        if (bv == BV) {
            int cand = 0x7fffffff;
#pragma unroll
            for (int k = 0; k < KP2; ++k) {
                if (dd[k].x == BV) cand = min(cand, tid + (2 * k) * BLOCK);
                if (dd[k].y == BV) cand = min(cand, tid + (2 * k + 1) * BLOCK);
            }
            atomicMin(&s_win[buf], cand);
        }
        __syncthreads();                            // barrier #2
        far = __builtin_amdgcn_readfirstlane(s_win[buf]);
    }
}

// ---------------------------------------------------------------------------
// Ball query, nsample=1: one wave per centroid; scan 64-point chunks from
// index 0, first hit wins (== min index within radius). Distance replicated
// as the reference einsum: ((-2*dot) + |c|^2) + |p|^2; keep-test d <= 0.25.
// ---------------------------------------------------------------------------
__global__ __launch_bounds__(256) void ballq_kernel(
    const float* __restrict__ xyz,   // [B,3,N]
    const int* __restrict__ cent,    // [B,NPOINT]
    int* __restrict__ out)           // [B,NPOINT]
{
    const int gw   = (blockIdx.x * 256 + threadIdx.x) >> 6; // global wave id
    const int lane = threadIdx.x & 63;
    const int b = gw / NPOINT;
    const int s = gw % NPOINT;

    const float* X = xyz + (size_t)b * 3 * N_PTS;
    const float* Y = X + N_PTS;
    const float* Z = X + 2 * N_PTS;

    const int ci = cent[b * NPOINT + s];
    const float cx = X[ci];
    const float cy = Y[ci];
    const float cz = Z[ci];
    const float cn = __fadd_rn(
        __fadd_rn(__fmul_rn(cx, cx), __fmul_rn(cy, cy)), __fmul_rn(cz, cz));

    int res = N_PTS;
    for (int base = 0; base < N_PTS; base += 64) {
        const int p = base + lane;
        const float x = X[p];
        const float y = Y[p];
        const float z = Z[p];
        const float dot = __fadd_rn(
            __fadd_rn(__fmul_rn(x, cx), __fmul_rn(y, cy)), __fmul_rn(z, cz));
        const float pn = __fadd_rn(
            __fadd_rn(__fmul_rn(x, x), __fmul_rn(y, y)), __fmul_rn(z, z));
        const float d = __fadd_rn(__fadd_rn(__fmul_rn(-2.0f, dot), cn), pn);
        const bool hit = !(d > 0.25f);
        const unsigned long long m = __ballot(hit);
        if (m) {                       // wave-uniform branch
            res = base + (__ffsll((long long)m) - 1);
            break;
        }
    }
    if (lane == 0) out[b * NPOINT + s] = res;
}

extern "C" void kernel_launch(void* const* d_in, const int* in_sizes, int n_in,
                              void* d_out, int out_size, void* d_ws, size_t ws_size,
                              hipStream_t stream) {
    const float* xyz = (const float*)d_in[0];
    const int B = in_sizes[1] / 16;          // cls_label is [B,16]
    int* cent = (int*)d_ws;                  // [B, NPOINT] scratch
    int* out  = (int*)d_out;                 // int32 [B, NPOINT, 1]

    fps_kernel<<<B, BLOCK, 0, stream>>>(xyz, cent);

    const int nwaves  = B * NPOINT;          // one wave per centroid
    const int nblocks = nwaves / 4;          // 256 threads = 4 waves/block
    ballq_kernel<<<nblocks, 256, 0, stream>>>(xyz, cent, out);
}